// Round 8
// baseline (402.134 us; speedup 1.0000x reference)
//
#include <hip/hip_runtime.h>
#include <hip/hip_bf16.h>

// Problem constants: N=100000 nodes, E=1200000 edges, D=64, K=3 hops.
#define GN 100000
#define GE 1200000
#define GD 64
#define SCAN_B 256

// WS budget note: round-4 showed ws_size < ~92 MB (overflow corrupted pristine
// inputs). This layout uses ~45 MB. Keep it well under 87.6.
//
// CSR entry is 4 B (src index only). Edge weight dinv[r]*dinv[c] is factored:
// dinv[c] is wave-uniform in the gather (c == node), so the gather computes
// acc = dinv[node] * sum_e dinv[r_e] * x_e. Halves fill's write-amplified
// scatter region (round-7 counters: WRITE_SIZE ~= lines x 8 XCDs x 64B).

// ---------------------------------------------------------------------------
// Runtime dtype detection. flags[0]=1 if weight/alpha bf16 else fp32.
// flags[1]=1 if edge_index int64 else int32.
// ---------------------------------------------------------------------------
__global__ void detect_kernel(const void* __restrict__ w,
                              const void* __restrict__ edge,
                              int* __restrict__ flags) {
    __shared__ int s_badw, s_edgenz;
    if (threadIdx.x == 0) { s_badw = 0; s_edgenz = 0; }
    __syncthreads();
    const unsigned short* wh = (const unsigned short*)w;
    const unsigned int*   ei = (const unsigned int*)edge;
    int badw = 0, edgenz = 0;
    for (int i = threadIdx.x; i < 4096; i += 256) {
        unsigned int bits = ((unsigned int)wh[i]) << 16;
        float v = __uint_as_float(bits);
        if (!(fabsf(v) <= 100.0f)) badw = 1;         // NaN/Inf/huge -> fp32 backing
        if ((i & 1) == 1 && ei[i] != 0u) edgenz = 1; // odd word nonzero -> int32
    }
    if (badw)   atomicOr(&s_badw, 1);
    if (edgenz) atomicOr(&s_edgenz, 1);
    __syncthreads();
    if (threadIdx.x == 0) {
        flags[0] = s_badw ? 0 : 1;
        flags[1] = s_edgenz ? 0 : 1;
    }
}

__device__ __forceinline__ int ld_row(const int* __restrict__ edge, int e, int e64) {
    return e64 ? edge[2 * (size_t)e] : edge[e];
}
__device__ __forceinline__ int ld_col(const int* __restrict__ edge, int e, int e64) {
    return e64 ? edge[2 * ((size_t)GE + (size_t)e)] : edge[(size_t)GE + (size_t)e];
}
__device__ __forceinline__ float ld_f(const void* __restrict__ p, size_t i, int bf16f) {
    if (bf16f) return __bfloat162float(((const __hip_bfloat16*)p)[i]);
    return ((const float*)p)[i];
}

// ---- int histogram of col ----
__global__ void hist_kernel(const int* __restrict__ edge, const int* __restrict__ flags,
                            int* __restrict__ degi, int E) {
    int e = blockIdx.x * blockDim.x + threadIdx.x;
    int e64 = flags[1];
    if (e < E) {
        int c = ld_col(edge, e, e64);
        if ((unsigned)c < (unsigned)GN) atomicAdd(&degi[c], 1);
    }
}

// ---- fused: block-level exclusive scan of degi + dinv computation ----
__global__ void scan1_kernel(const int* __restrict__ degi, int* __restrict__ excl,
                             int* __restrict__ bsums, float* __restrict__ dinv, int n) {
    __shared__ int s[SCAN_B];
    int i = blockIdx.x * SCAN_B + threadIdx.x;
    int v = (i < n) ? degi[i] : 0;
    if (i < n) dinv[i] = (v > 0) ? rsqrtf((float)v) : 0.0f;
    s[threadIdx.x] = v;
    __syncthreads();
    for (int off = 1; off < SCAN_B; off <<= 1) {
        int t = (threadIdx.x >= off) ? s[threadIdx.x - off] : 0;
        __syncthreads();
        s[threadIdx.x] += t;
        __syncthreads();
    }
    if (i < n) excl[i] = s[threadIdx.x] - v;
    if (threadIdx.x == SCAN_B - 1) bsums[blockIdx.x] = s[SCAN_B - 1];
}

__global__ void scan2_kernel(int* __restrict__ bsums, int nb) {
    __shared__ int s[512];
    int v = (threadIdx.x < nb) ? bsums[threadIdx.x] : 0;
    s[threadIdx.x] = v;
    __syncthreads();
    for (int off = 1; off < 512; off <<= 1) {
        int t = (threadIdx.x >= off) ? s[threadIdx.x - off] : 0;
        __syncthreads();
        s[threadIdx.x] += t;
        __syncthreads();
    }
    if (threadIdx.x < nb) bsums[threadIdx.x] = s[threadIdx.x] - v; // exclusive
}

__global__ void scan3_kernel(int* __restrict__ rowptr, const int* __restrict__ bsums, int n) {
    int i = blockIdx.x * SCAN_B + threadIdx.x;
    if (i < n) rowptr[i] += bsums[blockIdx.x];
}

// ---- CSR fill: 4 B entries (src only; shift trick on rowptr) ----
__global__ void fill_kernel(const int* __restrict__ edge, const int* __restrict__ flags,
                            int* __restrict__ rowptr, int* __restrict__ csr, int E) {
    int e = blockIdx.x * blockDim.x + threadIdx.x;
    int e64 = flags[1];
    if (e < E) {
        int r = ld_row(edge, e, e64);
        int c = ld_col(edge, e, e64);
        if ((unsigned)r < (unsigned)GN && (unsigned)c < (unsigned)GN) {
            int pos = atomicAdd(&rowptr[c], 1);
            csr[pos] = r;
        }
    }
}

// ---- X = bf16(weight); OUT = bf16(alpha[0] * weight) ----
__global__ void init_kernel(const void* __restrict__ w, const void* __restrict__ alpha,
                            const int* __restrict__ flags,
                            __hip_bfloat16* __restrict__ X, __hip_bfloat16* __restrict__ OUT,
                            int n) {
    int i = 4 * (blockIdx.x * blockDim.x + threadIdx.x);
    int wbf = flags[0];
    if (i < n) {
        float a0 = ld_f(alpha, 0, wbf);
        #pragma unroll
        for (int q = 0; q < 4; ++q) {
            float v = ld_f(w, i + q, wbf);
            X[i + q] = __float2bfloat16(v);        // hop-1 operand: exact bf16 input
            OUT[i + q] = __float2bfloat16(a0 * v);
        }
    }
}

// ---- one hop, gather form, fused axpy, 8-way unrolled; bf16 rows ----
// acc = dinv[node] * sum_e dinv[r_e] * X[r_e,:]; Y=bf16(acc); OUT += alpha_k*acc
__global__ void gather_kernel(const __hip_bfloat16* __restrict__ X,
                              __hip_bfloat16* __restrict__ Y,
                              __hip_bfloat16* __restrict__ OUT,
                              const int* __restrict__ rowptr, const int* __restrict__ csr,
                              const float* __restrict__ dinv,
                              const void* __restrict__ alpha, const int* __restrict__ flags,
                              int k, int N) {
    int t = blockIdx.x * blockDim.x + threadIdx.x;
    int node = __builtin_amdgcn_readfirstlane(t >> 6);
    int lane = t & 63;
    if (node >= N) return;
    int beg = node ? rowptr[node - 1] : 0;   // post-fill: rowptr[c] = end of segment c
    int end = rowptr[node];
    float dc = dinv[node];                   // wave-uniform factor dinv[col]
    float a0 = 0.0f, a1 = 0.0f, a2 = 0.0f, a3 = 0.0f;
    float a4 = 0.0f, a5 = 0.0f, a6 = 0.0f, a7 = 0.0f;
    int j = beg;
    for (; j + 8 <= end; j += 8) {
        int r0 = csr[j + 0]; int r1 = csr[j + 1];
        int r2 = csr[j + 2]; int r3 = csr[j + 3];
        int r4 = csr[j + 4]; int r5 = csr[j + 5];
        int r6 = csr[j + 6]; int r7 = csr[j + 7];
        float w0 = dinv[r0]; float w1 = dinv[r1];
        float w2 = dinv[r2]; float w3 = dinv[r3];
        float w4 = dinv[r4]; float w5 = dinv[r5];
        float w6 = dinv[r6]; float w7 = dinv[r7];
        float x0 = __bfloat162float(X[(size_t)r0 * GD + lane]);
        float x1 = __bfloat162float(X[(size_t)r1 * GD + lane]);
        float x2 = __bfloat162float(X[(size_t)r2 * GD + lane]);
        float x3 = __bfloat162float(X[(size_t)r3 * GD + lane]);
        float x4 = __bfloat162float(X[(size_t)r4 * GD + lane]);
        float x5 = __bfloat162float(X[(size_t)r5 * GD + lane]);
        float x6 = __bfloat162float(X[(size_t)r6 * GD + lane]);
        float x7 = __bfloat162float(X[(size_t)r7 * GD + lane]);
        a0 = fmaf(w0, x0, a0);
        a1 = fmaf(w1, x1, a1);
        a2 = fmaf(w2, x2, a2);
        a3 = fmaf(w3, x3, a3);
        a4 = fmaf(w4, x4, a4);
        a5 = fmaf(w5, x5, a5);
        a6 = fmaf(w6, x6, a6);
        a7 = fmaf(w7, x7, a7);
    }
    if (j + 4 <= end) {
        int r0 = csr[j + 0]; int r1 = csr[j + 1];
        int r2 = csr[j + 2]; int r3 = csr[j + 3];
        float w0 = dinv[r0]; float w1 = dinv[r1];
        float w2 = dinv[r2]; float w3 = dinv[r3];
        float x0 = __bfloat162float(X[(size_t)r0 * GD + lane]);
        float x1 = __bfloat162float(X[(size_t)r1 * GD + lane]);
        float x2 = __bfloat162float(X[(size_t)r2 * GD + lane]);
        float x3 = __bfloat162float(X[(size_t)r3 * GD + lane]);
        a0 = fmaf(w0, x0, a0);
        a1 = fmaf(w1, x1, a1);
        a2 = fmaf(w2, x2, a2);
        a3 = fmaf(w3, x3, a3);
        j += 4;
    }
    for (; j < end; ++j) {
        int r = csr[j];
        a0 = fmaf(dinv[r], __bfloat162float(X[(size_t)r * GD + lane]), a0);
    }
    float acc = dc * (((a0 + a1) + (a2 + a3)) + ((a4 + a5) + (a6 + a7)));
    size_t o = (size_t)node * GD + lane;
    Y[o] = __float2bfloat16(acc);
    float a = ld_f(alpha, k, flags[0]);
    OUT[o] = __float2bfloat16(__bfloat162float(OUT[o]) + a * acc);
}

// ---- bf16-pair dot helper: 2 elements per uint ----
__device__ __forceinline__ float dot2_bf16(unsigned ua, unsigned ub) {
    float al = __uint_as_float(ua << 16);
    float ah = __uint_as_float(ua & 0xFFFF0000u);
    float bl = __uint_as_float(ub << 16);
    float bh = __uint_as_float(ub & 0xFFFF0000u);
    return fmaf(al, bl, ah * bh);
}

// ---- res[e] = dot(OUT[row[e]], OUT[col[e]]) — 8 threads/edge, 16B loads ----
__global__ void dot_kernel(const __hip_bfloat16* __restrict__ OUT,
                           const int* __restrict__ edge, const int* __restrict__ flags,
                           void* __restrict__ res, int E) {
    int t = blockIdx.x * blockDim.x + threadIdx.x;
    int e = t >> 3;
    int sub = t & 7;
    if (e >= E) return;
    int e64 = flags[1];
    int wbf = flags[0];
    int r = ld_row(edge, e, e64);
    int c = ld_col(edge, e, e64);
    float p = 0.0f;
    if ((unsigned)r < (unsigned)GN && (unsigned)c < (unsigned)GN) {
        uint4 ua = *(const uint4*)(OUT + (size_t)r * GD + sub * 8);
        uint4 ub = *(const uint4*)(OUT + (size_t)c * GD + sub * 8);
        p = (dot2_bf16(ua.x, ub.x) + dot2_bf16(ua.y, ub.y)) +
            (dot2_bf16(ua.z, ub.z) + dot2_bf16(ua.w, ub.w));
    }
    #pragma unroll
    for (int off = 4; off > 0; off >>= 1) p += __shfl_down(p, off, 8);
    if (sub == 0) {
        if (wbf) ((__hip_bfloat16*)res)[e] = __float2bfloat16(p);
        else     ((float*)res)[e] = p;
    }
}

extern "C" void kernel_launch(void* const* d_in, const int* in_sizes, int n_in,
                              void* d_out, int out_size, void* d_ws, size_t ws_size,
                              hipStream_t stream) {
    const int E = GE, N = GN, ND = GN * GD;
    const int nblocks_scan = (N + SCAN_B - 1) / SCAN_B;  // 391

    const void* edge   = d_in[0];
    const void* weight = d_in[1];
    const void* alpha  = d_in[2];

    // Workspace layout (~45 MB total)
    char* ws = (char*)d_ws;
    int*   flags  = (int*)ws;   ws += 256;
    int*   degi   = (int*)ws;   ws += (((size_t)N * 4 + 255) / 256) * 256;
    float* dinv   = (float*)ws; ws += (((size_t)N * 4 + 255) / 256) * 256;
    int*   rowptr = (int*)ws;   ws += (((size_t)N * 4 + 255) / 256) * 256;
    int*   bsums  = (int*)ws;   ws += 2048;
    int*   csr    = (int*)ws;   ws += (size_t)E * 4;              // 4.8 MB
    __hip_bfloat16* X   = (__hip_bfloat16*)ws; ws += (size_t)ND * 2;  // 12.8 MB
    __hip_bfloat16* Y   = (__hip_bfloat16*)ws; ws += (size_t)ND * 2;  // 12.8 MB
    __hip_bfloat16* OUT = (__hip_bfloat16*)ws; ws += (size_t)ND * 2;  // 12.8 MB

    const int B = 256;

    detect_kernel<<<1, 256, 0, stream>>>(weight, edge, flags);

    // CSR build
    hipMemsetAsync(degi, 0, (size_t)N * 4, stream);
    hist_kernel<<<(E + B - 1) / B, B, 0, stream>>>((const int*)edge, flags, degi, E);
    scan1_kernel<<<nblocks_scan, SCAN_B, 0, stream>>>(degi, rowptr, bsums, dinv, N);
    scan2_kernel<<<1, 512, 0, stream>>>(bsums, nblocks_scan);
    scan3_kernel<<<nblocks_scan, SCAN_B, 0, stream>>>(rowptr, bsums, N);
    fill_kernel<<<(E + B - 1) / B, B, 0, stream>>>((const int*)edge, flags, rowptr, csr, E);

    // X = bf16(weight); OUT = bf16(a0*weight)
    init_kernel<<<(ND / 4 + B - 1) / B, B, 0, stream>>>(weight, alpha, flags, X, OUT, ND);

    // 3 propagation hops (gather + fused axpy, 8-way unrolled, bf16 rows)
    const int ggrid = (int)(((size_t)N * 64 + B - 1) / B);
    gather_kernel<<<ggrid, B, 0, stream>>>(X, Y, OUT, rowptr, csr, dinv, alpha, flags, 1, N);
    gather_kernel<<<ggrid, B, 0, stream>>>(Y, X, OUT, rowptr, csr, dinv, alpha, flags, 2, N);
    gather_kernel<<<ggrid, B, 0, stream>>>(X, Y, OUT, rowptr, csr, dinv, alpha, flags, 3, N);

    // per-edge link scores (8 threads/edge, uint4 row loads)
    dot_kernel<<<(int)(((size_t)E * 8 + B - 1) / B), B, 0, stream>>>(OUT, (const int*)edge, flags, d_out, E);
}

// Round 9
// 380.392 us; speedup vs baseline: 1.0572x; 1.0572x over previous
//
#include <hip/hip_runtime.h>
#include <hip/hip_bf16.h>

// Problem constants: N=100000 nodes, E=1200000 edges, D=64, K=3 hops.
#define GN 100000
#define GE 1200000
#define GD 64
#define SCAN_B 256
#define NXCD 8
#define COLS_PER_GROUP ((GN + NXCD - 1) / NXCD)   // 12500

// WS budget: round-4 showed ws_size < ~92 MB (overflow corrupted pristine
// inputs). This layout uses ~45 MB.
//
// fill write-amplification history (rocprof WRITE_SIZE):
//   r7: 8B entries, random scatter  -> 78 MB (~E*64B), 58 us
//   r8: 4B entries, random scatter  -> 83 MB, 96 us  (more XCDs/line = worse)
// Mechanism: interleaved stores to one line from DIFFERENT XCDs cost a full
// 64B coherence writeback per access. Fix: col-range partition fill so each
// CSR line is written by blocks of a single (blockIdx%8) group -> one XCD.

// ---------------------------------------------------------------------------
// Runtime dtype detection. flags[0]=1 if weight/alpha bf16 else fp32.
// flags[1]=1 if edge_index int64 else int32.
// ---------------------------------------------------------------------------
__global__ void detect_kernel(const void* __restrict__ w,
                              const void* __restrict__ edge,
                              int* __restrict__ flags) {
    __shared__ int s_badw, s_edgenz;
    if (threadIdx.x == 0) { s_badw = 0; s_edgenz = 0; }
    __syncthreads();
    const unsigned short* wh = (const unsigned short*)w;
    const unsigned int*   ei = (const unsigned int*)edge;
    int badw = 0, edgenz = 0;
    for (int i = threadIdx.x; i < 4096; i += 256) {
        unsigned int bits = ((unsigned int)wh[i]) << 16;
        float v = __uint_as_float(bits);
        if (!(fabsf(v) <= 100.0f)) badw = 1;         // NaN/Inf/huge -> fp32 backing
        if ((i & 1) == 1 && ei[i] != 0u) edgenz = 1; // odd word nonzero -> int32
    }
    if (badw)   atomicOr(&s_badw, 1);
    if (edgenz) atomicOr(&s_edgenz, 1);
    __syncthreads();
    if (threadIdx.x == 0) {
        flags[0] = s_badw ? 0 : 1;
        flags[1] = s_edgenz ? 0 : 1;
    }
}

__device__ __forceinline__ int ld_row(const int* __restrict__ edge, int e, int e64) {
    return e64 ? edge[2 * (size_t)e] : edge[e];
}
__device__ __forceinline__ int ld_col(const int* __restrict__ edge, int e, int e64) {
    return e64 ? edge[2 * ((size_t)GE + (size_t)e)] : edge[(size_t)GE + (size_t)e];
}
__device__ __forceinline__ float ld_f(const void* __restrict__ p, size_t i, int bf16f) {
    if (bf16f) return __bfloat162float(((const __hip_bfloat16*)p)[i]);
    return ((const float*)p)[i];
}

// ---- int histogram of col ----
__global__ void hist_kernel(const int* __restrict__ edge, const int* __restrict__ flags,
                            int* __restrict__ degi, int E) {
    int e = blockIdx.x * blockDim.x + threadIdx.x;
    int e64 = flags[1];
    if (e < E) {
        int c = ld_col(edge, e, e64);
        if ((unsigned)c < (unsigned)GN) atomicAdd(&degi[c], 1);
    }
}

// ---- fused: block-level exclusive scan of degi + dinv computation ----
__global__ void scan1_kernel(const int* __restrict__ degi, int* __restrict__ excl,
                             int* __restrict__ bsums, float* __restrict__ dinv, int n) {
    __shared__ int s[SCAN_B];
    int i = blockIdx.x * SCAN_B + threadIdx.x;
    int v = (i < n) ? degi[i] : 0;
    if (i < n) dinv[i] = (v > 0) ? rsqrtf((float)v) : 0.0f;
    s[threadIdx.x] = v;
    __syncthreads();
    for (int off = 1; off < SCAN_B; off <<= 1) {
        int t = (threadIdx.x >= off) ? s[threadIdx.x - off] : 0;
        __syncthreads();
        s[threadIdx.x] += t;
        __syncthreads();
    }
    if (i < n) excl[i] = s[threadIdx.x] - v;
    if (threadIdx.x == SCAN_B - 1) bsums[blockIdx.x] = s[SCAN_B - 1];
}

__global__ void scan2_kernel(int* __restrict__ bsums, int nb) {
    __shared__ int s[512];
    int v = (threadIdx.x < nb) ? bsums[threadIdx.x] : 0;
    s[threadIdx.x] = v;
    __syncthreads();
    for (int off = 1; off < 512; off <<= 1) {
        int t = (threadIdx.x >= off) ? s[threadIdx.x - off] : 0;
        __syncthreads();
        s[threadIdx.x] += t;
        __syncthreads();
    }
    if (threadIdx.x < nb) bsums[threadIdx.x] = s[threadIdx.x] - v; // exclusive
}

__global__ void scan3_kernel(int* __restrict__ rowptr, const int* __restrict__ bsums, int n) {
    int i = blockIdx.x * SCAN_B + threadIdx.x;
    if (i < n) rowptr[i] += bsums[blockIdx.x];
}

// ---- CSR fill, XCD-affine: group g=blockIdx&7 writes only cols in its range.
// With round-robin block->XCD dispatch, each CSR line is written by one XCD.
__global__ void fill_kernel(const int* __restrict__ edge, const int* __restrict__ flags,
                            int* __restrict__ rowptr, int* __restrict__ csr,
                            int E, int chunkSize) {
    int g = blockIdx.x & (NXCD - 1);
    int chunk = blockIdx.x >> 3;
    int lo = g * COLS_PER_GROUP;
    int hi = lo + COLS_PER_GROUP;  // <= GN guaranteed by range filter below
    int e64 = flags[1];
    int base = chunk * chunkSize;
    int endE = min(base + chunkSize, E);
    for (int e = base + (int)threadIdx.x; e < endE; e += (int)blockDim.x) {
        int c = ld_col(edge, e, e64);
        if (c >= lo && c < hi && c < GN) {
            int r = ld_row(edge, e, e64);
            if ((unsigned)r < (unsigned)GN) {
                int pos = atomicAdd(&rowptr[c], 1);
                csr[pos] = r;
            }
        }
    }
}

// ---- X = bf16(weight); OUT = bf16(alpha[0] * weight) ----
__global__ void init_kernel(const void* __restrict__ w, const void* __restrict__ alpha,
                            const int* __restrict__ flags,
                            __hip_bfloat16* __restrict__ X, __hip_bfloat16* __restrict__ OUT,
                            int n) {
    int i = 4 * (blockIdx.x * blockDim.x + threadIdx.x);
    int wbf = flags[0];
    if (i < n) {
        float a0 = ld_f(alpha, 0, wbf);
        #pragma unroll
        for (int q = 0; q < 4; ++q) {
            float v = ld_f(w, i + q, wbf);
            X[i + q] = __float2bfloat16(v);        // hop-1 operand: exact bf16 input
            OUT[i + q] = __float2bfloat16(a0 * v);
        }
    }
}

// ---- one hop, gather form, fused axpy, 8-way unrolled; bf16 rows ----
// acc = dinv[node] * sum_e dinv[r_e] * X[r_e,:]; Y=bf16(acc) (skipped on last
// hop - dead store); OUT += alpha_k*acc
__global__ void gather_kernel(const __hip_bfloat16* __restrict__ X,
                              __hip_bfloat16* __restrict__ Y,
                              __hip_bfloat16* __restrict__ OUT,
                              const int* __restrict__ rowptr, const int* __restrict__ csr,
                              const float* __restrict__ dinv,
                              const void* __restrict__ alpha, const int* __restrict__ flags,
                              int k, int store_y, int N) {
    int t = blockIdx.x * blockDim.x + threadIdx.x;
    int node = __builtin_amdgcn_readfirstlane(t >> 6);
    int lane = t & 63;
    if (node >= N) return;
    int beg = node ? rowptr[node - 1] : 0;   // post-fill: rowptr[c] = end of segment c
    int end = rowptr[node];
    float dc = dinv[node];                   // wave-uniform factor dinv[col]
    float a0 = 0.0f, a1 = 0.0f, a2 = 0.0f, a3 = 0.0f;
    float a4 = 0.0f, a5 = 0.0f, a6 = 0.0f, a7 = 0.0f;
    int j = beg;
    for (; j + 8 <= end; j += 8) {
        int r0 = csr[j + 0]; int r1 = csr[j + 1];
        int r2 = csr[j + 2]; int r3 = csr[j + 3];
        int r4 = csr[j + 4]; int r5 = csr[j + 5];
        int r6 = csr[j + 6]; int r7 = csr[j + 7];
        float w0 = dinv[r0]; float w1 = dinv[r1];
        float w2 = dinv[r2]; float w3 = dinv[r3];
        float w4 = dinv[r4]; float w5 = dinv[r5];
        float w6 = dinv[r6]; float w7 = dinv[r7];
        float x0 = __bfloat162float(X[(size_t)r0 * GD + lane]);
        float x1 = __bfloat162float(X[(size_t)r1 * GD + lane]);
        float x2 = __bfloat162float(X[(size_t)r2 * GD + lane]);
        float x3 = __bfloat162float(X[(size_t)r3 * GD + lane]);
        float x4 = __bfloat162float(X[(size_t)r4 * GD + lane]);
        float x5 = __bfloat162float(X[(size_t)r5 * GD + lane]);
        float x6 = __bfloat162float(X[(size_t)r6 * GD + lane]);
        float x7 = __bfloat162float(X[(size_t)r7 * GD + lane]);
        a0 = fmaf(w0, x0, a0);
        a1 = fmaf(w1, x1, a1);
        a2 = fmaf(w2, x2, a2);
        a3 = fmaf(w3, x3, a3);
        a4 = fmaf(w4, x4, a4);
        a5 = fmaf(w5, x5, a5);
        a6 = fmaf(w6, x6, a6);
        a7 = fmaf(w7, x7, a7);
    }
    if (j + 4 <= end) {
        int r0 = csr[j + 0]; int r1 = csr[j + 1];
        int r2 = csr[j + 2]; int r3 = csr[j + 3];
        float w0 = dinv[r0]; float w1 = dinv[r1];
        float w2 = dinv[r2]; float w3 = dinv[r3];
        float x0 = __bfloat162float(X[(size_t)r0 * GD + lane]);
        float x1 = __bfloat162float(X[(size_t)r1 * GD + lane]);
        float x2 = __bfloat162float(X[(size_t)r2 * GD + lane]);
        float x3 = __bfloat162float(X[(size_t)r3 * GD + lane]);
        a0 = fmaf(w0, x0, a0);
        a1 = fmaf(w1, x1, a1);
        a2 = fmaf(w2, x2, a2);
        a3 = fmaf(w3, x3, a3);
        j += 4;
    }
    for (; j < end; ++j) {
        int r = csr[j];
        a0 = fmaf(dinv[r], __bfloat162float(X[(size_t)r * GD + lane]), a0);
    }
    float acc = dc * (((a0 + a1) + (a2 + a3)) + ((a4 + a5) + (a6 + a7)));
    size_t o = (size_t)node * GD + lane;
    if (store_y) Y[o] = __float2bfloat16(acc);
    float a = ld_f(alpha, k, flags[0]);
    OUT[o] = __float2bfloat16(__bfloat162float(OUT[o]) + a * acc);
}

// ---- bf16-pair dot helper: 2 elements per uint ----
__device__ __forceinline__ float dot2_bf16(unsigned ua, unsigned ub) {
    float al = __uint_as_float(ua << 16);
    float ah = __uint_as_float(ua & 0xFFFF0000u);
    float bl = __uint_as_float(ub << 16);
    float bh = __uint_as_float(ub & 0xFFFF0000u);
    return fmaf(al, bl, ah * bh);
}

// ---- res[e] = dot(OUT[row[e]], OUT[col[e]]) — 8 threads/edge, 16B loads ----
__global__ void dot_kernel(const __hip_bfloat16* __restrict__ OUT,
                           const int* __restrict__ edge, const int* __restrict__ flags,
                           void* __restrict__ res, int E) {
    int t = blockIdx.x * blockDim.x + threadIdx.x;
    int e = t >> 3;
    int sub = t & 7;
    if (e >= E) return;
    int e64 = flags[1];
    int wbf = flags[0];
    int r = ld_row(edge, e, e64);
    int c = ld_col(edge, e, e64);
    float p = 0.0f;
    if ((unsigned)r < (unsigned)GN && (unsigned)c < (unsigned)GN) {
        uint4 ua = *(const uint4*)(OUT + (size_t)r * GD + sub * 8);
        uint4 ub = *(const uint4*)(OUT + (size_t)c * GD + sub * 8);
        p = (dot2_bf16(ua.x, ub.x) + dot2_bf16(ua.y, ub.y)) +
            (dot2_bf16(ua.z, ub.z) + dot2_bf16(ua.w, ub.w));
    }
    #pragma unroll
    for (int off = 4; off > 0; off >>= 1) p += __shfl_down(p, off, 8);
    if (sub == 0) {
        if (wbf) ((__hip_bfloat16*)res)[e] = __float2bfloat16(p);
        else     ((float*)res)[e] = p;
    }
}

extern "C" void kernel_launch(void* const* d_in, const int* in_sizes, int n_in,
                              void* d_out, int out_size, void* d_ws, size_t ws_size,
                              hipStream_t stream) {
    const int E = GE, N = GN, ND = GN * GD;
    const int nblocks_scan = (N + SCAN_B - 1) / SCAN_B;  // 391

    const void* edge   = d_in[0];
    const void* weight = d_in[1];
    const void* alpha  = d_in[2];

    // Workspace layout (~45 MB total)
    char* ws = (char*)d_ws;
    int*   flags  = (int*)ws;   ws += 256;
    int*   degi   = (int*)ws;   ws += (((size_t)N * 4 + 255) / 256) * 256;
    float* dinv   = (float*)ws; ws += (((size_t)N * 4 + 255) / 256) * 256;
    int*   rowptr = (int*)ws;   ws += (((size_t)N * 4 + 255) / 256) * 256;
    int*   bsums  = (int*)ws;   ws += 2048;
    int*   csr    = (int*)ws;   ws += (size_t)E * 4;              // 4.8 MB
    __hip_bfloat16* X   = (__hip_bfloat16*)ws; ws += (size_t)ND * 2;  // 12.8 MB
    __hip_bfloat16* Y   = (__hip_bfloat16*)ws; ws += (size_t)ND * 2;  // 12.8 MB
    __hip_bfloat16* OUT = (__hip_bfloat16*)ws; ws += (size_t)ND * 2;  // 12.8 MB

    const int B = 256;

    detect_kernel<<<1, 256, 0, stream>>>(weight, edge, flags);

    // CSR build
    hipMemsetAsync(degi, 0, (size_t)N * 4, stream);
    hist_kernel<<<(E + B - 1) / B, B, 0, stream>>>((const int*)edge, flags, degi, E);
    scan1_kernel<<<nblocks_scan, SCAN_B, 0, stream>>>(degi, rowptr, bsums, dinv, N);
    scan2_kernel<<<1, 512, 0, stream>>>(bsums, nblocks_scan);
    scan3_kernel<<<nblocks_scan, SCAN_B, 0, stream>>>(rowptr, bsums, N);
    // XCD-affine fill: 8 col-range groups x 384 edge chunks
    {
        const int G = 384;
        const int chunkSize = (E + G - 1) / G;   // 3125
        fill_kernel<<<NXCD * G, B, 0, stream>>>((const int*)edge, flags, rowptr, csr,
                                                E, chunkSize);
    }

    // X = bf16(weight); OUT = bf16(a0*weight)
    init_kernel<<<(ND / 4 + B - 1) / B, B, 0, stream>>>(weight, alpha, flags, X, OUT, ND);

    // 3 propagation hops (gather + fused axpy, 8-way unrolled, bf16 rows)
    const int ggrid = (int)(((size_t)N * 64 + B - 1) / B);
    gather_kernel<<<ggrid, B, 0, stream>>>(X, Y, OUT, rowptr, csr, dinv, alpha, flags, 1, 1, N);
    gather_kernel<<<ggrid, B, 0, stream>>>(Y, X, OUT, rowptr, csr, dinv, alpha, flags, 2, 1, N);
    gather_kernel<<<ggrid, B, 0, stream>>>(X, Y, OUT, rowptr, csr, dinv, alpha, flags, 3, 0, N);

    // per-edge link scores (8 threads/edge, uint4 row loads)
    dot_kernel<<<(int)(((size_t)E * 8 + B - 1) / B), B, 0, stream>>>(OUT, (const int*)edge, flags, d_out, E);
}

// Round 10
// 375.747 us; speedup vs baseline: 1.0702x; 1.0124x over previous
//
#include <hip/hip_runtime.h>
#include <hip/hip_bf16.h>

// Problem constants: N=100000 nodes, E=1200000 edges, D=64, K=3 hops.
#define GN 100000
#define GE 1200000
#define GD 64
#define SCAN_B 256
#define NXCD 8
#define COLS_PER_GROUP ((GN + NXCD - 1) / NXCD)   // 12500

// WS budget: round-4 showed ws_size < ~92 MB (overflow corrupted pristine
// inputs). This layout uses ~45 MB.
//
// fill write-amplification history (rocprof WRITE_SIZE):
//   r7: 8B entries, random scatter  -> 78 MB (~E*64B), 58 us
//   r8: 4B entries, random scatter  -> 83 MB, 96 us  (more XCDs/line = worse)
//   r9: 4B entries, XCD-affine      -> 50 MB, 57 us  (partial fix)
// Mechanism: interleaved stores to one line from DIFFERENT XCDs cost a full
// 64B coherence writeback per access; %8 block->XCD affinity only partially
// isolates lines. Further fix would need true radix partitioning.

// ---------------------------------------------------------------------------
// Runtime dtype detection. flags[0]=1 if weight/alpha bf16 else fp32.
// flags[1]=1 if edge_index int64 else int32.
// ---------------------------------------------------------------------------
__global__ void detect_kernel(const void* __restrict__ w,
                              const void* __restrict__ edge,
                              int* __restrict__ flags) {
    __shared__ int s_badw, s_edgenz;
    if (threadIdx.x == 0) { s_badw = 0; s_edgenz = 0; }
    __syncthreads();
    const unsigned short* wh = (const unsigned short*)w;
    const unsigned int*   ei = (const unsigned int*)edge;
    int badw = 0, edgenz = 0;
    for (int i = threadIdx.x; i < 4096; i += 256) {
        unsigned int bits = ((unsigned int)wh[i]) << 16;
        float v = __uint_as_float(bits);
        if (!(fabsf(v) <= 100.0f)) badw = 1;         // NaN/Inf/huge -> fp32 backing
        if ((i & 1) == 1 && ei[i] != 0u) edgenz = 1; // odd word nonzero -> int32
    }
    if (badw)   atomicOr(&s_badw, 1);
    if (edgenz) atomicOr(&s_edgenz, 1);
    __syncthreads();
    if (threadIdx.x == 0) {
        flags[0] = s_badw ? 0 : 1;
        flags[1] = s_edgenz ? 0 : 1;
    }
}

__device__ __forceinline__ int ld_row(const int* __restrict__ edge, int e, int e64) {
    return e64 ? edge[2 * (size_t)e] : edge[e];
}
__device__ __forceinline__ int ld_col(const int* __restrict__ edge, int e, int e64) {
    return e64 ? edge[2 * ((size_t)GE + (size_t)e)] : edge[(size_t)GE + (size_t)e];
}
__device__ __forceinline__ float ld_f(const void* __restrict__ p, size_t i, int bf16f) {
    if (bf16f) return __bfloat162float(((const __hip_bfloat16*)p)[i]);
    return ((const float*)p)[i];
}

__device__ __forceinline__ float bf_lo(unsigned u) { return __uint_as_float(u << 16); }
__device__ __forceinline__ float bf_hi(unsigned u) { return __uint_as_float(u & 0xFFFF0000u); }
__device__ __forceinline__ unsigned bf16bits(float f) {
    __hip_bfloat16 h = __float2bfloat16(f);
    unsigned short s;
    __builtin_memcpy(&s, &h, 2);
    return (unsigned)s;
}

// ---- int histogram of col ----
__global__ void hist_kernel(const int* __restrict__ edge, const int* __restrict__ flags,
                            int* __restrict__ degi, int E) {
    int e = blockIdx.x * blockDim.x + threadIdx.x;
    int e64 = flags[1];
    if (e < E) {
        int c = ld_col(edge, e, e64);
        if ((unsigned)c < (unsigned)GN) atomicAdd(&degi[c], 1);
    }
}

// ---- fused: block-level exclusive scan of degi + dinv computation ----
__global__ void scan1_kernel(const int* __restrict__ degi, int* __restrict__ excl,
                             int* __restrict__ bsums, float* __restrict__ dinv, int n) {
    __shared__ int s[SCAN_B];
    int i = blockIdx.x * SCAN_B + threadIdx.x;
    int v = (i < n) ? degi[i] : 0;
    if (i < n) dinv[i] = (v > 0) ? rsqrtf((float)v) : 0.0f;
    s[threadIdx.x] = v;
    __syncthreads();
    for (int off = 1; off < SCAN_B; off <<= 1) {
        int t = (threadIdx.x >= off) ? s[threadIdx.x - off] : 0;
        __syncthreads();
        s[threadIdx.x] += t;
        __syncthreads();
    }
    if (i < n) excl[i] = s[threadIdx.x] - v;
    if (threadIdx.x == SCAN_B - 1) bsums[blockIdx.x] = s[SCAN_B - 1];
}

__global__ void scan2_kernel(int* __restrict__ bsums, int nb) {
    __shared__ int s[512];
    int v = (threadIdx.x < nb) ? bsums[threadIdx.x] : 0;
    s[threadIdx.x] = v;
    __syncthreads();
    for (int off = 1; off < 512; off <<= 1) {
        int t = (threadIdx.x >= off) ? s[threadIdx.x - off] : 0;
        __syncthreads();
        s[threadIdx.x] += t;
        __syncthreads();
    }
    if (threadIdx.x < nb) bsums[threadIdx.x] = s[threadIdx.x] - v; // exclusive
}

__global__ void scan3_kernel(int* __restrict__ rowptr, const int* __restrict__ bsums, int n) {
    int i = blockIdx.x * SCAN_B + threadIdx.x;
    if (i < n) rowptr[i] += bsums[blockIdx.x];
}

// ---- CSR fill, XCD-affine: group g=blockIdx&7 writes only cols in its range ----
__global__ void fill_kernel(const int* __restrict__ edge, const int* __restrict__ flags,
                            int* __restrict__ rowptr, int* __restrict__ csr,
                            int E, int chunkSize) {
    int g = blockIdx.x & (NXCD - 1);
    int chunk = blockIdx.x >> 3;
    int lo = g * COLS_PER_GROUP;
    int hi = lo + COLS_PER_GROUP;
    int e64 = flags[1];
    int base = chunk * chunkSize;
    int endE = min(base + chunkSize, E);
    for (int e = base + (int)threadIdx.x; e < endE; e += (int)blockDim.x) {
        int c = ld_col(edge, e, e64);
        if (c >= lo && c < hi && c < GN) {
            int r = ld_row(edge, e, e64);
            if ((unsigned)r < (unsigned)GN) {
                int pos = atomicAdd(&rowptr[c], 1);
                csr[pos] = r;
            }
        }
    }
}

// ---- X = bf16(weight); OUT = bf16(alpha[0] * weight) ----
__global__ void init_kernel(const void* __restrict__ w, const void* __restrict__ alpha,
                            const int* __restrict__ flags,
                            __hip_bfloat16* __restrict__ X, __hip_bfloat16* __restrict__ OUT,
                            int n) {
    int i = 4 * (blockIdx.x * blockDim.x + threadIdx.x);
    int wbf = flags[0];
    if (i < n) {
        float a0 = ld_f(alpha, 0, wbf);
        #pragma unroll
        for (int q = 0; q < 4; ++q) {
            float v = ld_f(w, i + q, wbf);
            X[i + q] = __float2bfloat16(v);        // hop-1 operand: exact bf16 input
            OUT[i + q] = __float2bfloat16(a0 * v);
        }
    }
}

// ---- one hop, gather form, fused axpy; 2 edges/wave-step, packed uint loads ----
// lane = 32*h + i: h selects edge of pair, i selects dim-pair (dims 2i, 2i+1).
// acc = dinv[node] * sum_e dinv[r_e] * X[r_e,:]; Y=bf16(acc) (skipped last hop);
// OUT += alpha_k * acc.
__global__ void gather_kernel(const __hip_bfloat16* __restrict__ X,
                              __hip_bfloat16* __restrict__ Y,
                              __hip_bfloat16* __restrict__ OUT,
                              const int* __restrict__ rowptr, const int* __restrict__ csr,
                              const float* __restrict__ dinv,
                              const void* __restrict__ alpha, const int* __restrict__ flags,
                              int k, int store_y, int N) {
    int t = blockIdx.x * blockDim.x + threadIdx.x;
    int node = __builtin_amdgcn_readfirstlane(t >> 6);
    if (node >= N) return;
    int lane = t & 63;
    int h = lane >> 5;        // which edge of the pair
    int i = lane & 31;        // dim-pair index
    int beg = node ? rowptr[node - 1] : 0;   // post-fill: rowptr[c] = segment end
    int end = rowptr[node];
    float dc = dinv[node];                   // wave-uniform factor dinv[col]
    float ax0 = 0.0f, ay0 = 0.0f, ax1 = 0.0f, ay1 = 0.0f;
    float ax2 = 0.0f, ay2 = 0.0f, ax3 = 0.0f, ay3 = 0.0f;
    int j = beg;
    // main: 4 pairs = 8 edges per iteration
    for (; j + 8 <= end; j += 8) {
        int r0 = csr[j + 0 + h];
        int r1 = csr[j + 2 + h];
        int r2 = csr[j + 4 + h];
        int r3 = csr[j + 6 + h];
        float w0 = dinv[r0]; float w1 = dinv[r1];
        float w2 = dinv[r2]; float w3 = dinv[r3];
        unsigned u0 = *(const unsigned*)(X + (size_t)r0 * GD + 2 * i);
        unsigned u1 = *(const unsigned*)(X + (size_t)r1 * GD + 2 * i);
        unsigned u2 = *(const unsigned*)(X + (size_t)r2 * GD + 2 * i);
        unsigned u3 = *(const unsigned*)(X + (size_t)r3 * GD + 2 * i);
        ax0 = fmaf(w0, bf_lo(u0), ax0); ay0 = fmaf(w0, bf_hi(u0), ay0);
        ax1 = fmaf(w1, bf_lo(u1), ax1); ay1 = fmaf(w1, bf_hi(u1), ay1);
        ax2 = fmaf(w2, bf_lo(u2), ax2); ay2 = fmaf(w2, bf_hi(u2), ay2);
        ax3 = fmaf(w3, bf_lo(u3), ax3); ay3 = fmaf(w3, bf_hi(u3), ay3);
    }
    // pair tail
    for (; j + 2 <= end; j += 2) {
        int r = csr[j + h];
        float w = dinv[r];
        unsigned u = *(const unsigned*)(X + (size_t)r * GD + 2 * i);
        ax0 = fmaf(w, bf_lo(u), ax0); ay0 = fmaf(w, bf_hi(u), ay0);
    }
    // odd single edge: only h==0 contributes
    if (j < end) {
        int r = csr[j];
        float w = (h == 0) ? dinv[r] : 0.0f;
        unsigned u = *(const unsigned*)(X + (size_t)r * GD + 2 * i);
        ax0 = fmaf(w, bf_lo(u), ax0); ay0 = fmaf(w, bf_hi(u), ay0);
    }
    float accx = (ax0 + ax1) + (ax2 + ax3);
    float accy = (ay0 + ay1) + (ay2 + ay3);
    // combine the two edge-halves (disjoint edge subsets)
    accx += __shfl_xor(accx, 32, 64);
    accy += __shfl_xor(accy, 32, 64);
    accx *= dc; accy *= dc;
    float a = ld_f(alpha, k, flags[0]);
    if (h == 0) {
        __hip_bfloat16* yp = Y + (size_t)node * GD + 2 * i;
        __hip_bfloat16* op = OUT + (size_t)node * GD + 2 * i;
        if (store_y) {
            unsigned pack = (bf16bits(accy) << 16) | bf16bits(accx);
            *(unsigned*)yp = pack;
        }
        unsigned uo = *(const unsigned*)op;
        float ox = fmaf(a, accx, bf_lo(uo));
        float oy = fmaf(a, accy, bf_hi(uo));
        *(unsigned*)op = (bf16bits(oy) << 16) | bf16bits(ox);
    }
}

// ---- bf16-pair dot helper: 2 elements per uint ----
__device__ __forceinline__ float dot2_bf16(unsigned ua, unsigned ub) {
    return fmaf(bf_lo(ua), bf_lo(ub), bf_hi(ua) * bf_hi(ub));
}

// ---- res[e] = dot(OUT[row[e]], OUT[col[e]]) — 4 threads/edge, 2x16B per row ----
__global__ void dot_kernel(const __hip_bfloat16* __restrict__ OUT,
                           const int* __restrict__ edge, const int* __restrict__ flags,
                           void* __restrict__ res, int E) {
    int t = blockIdx.x * blockDim.x + threadIdx.x;
    int e = t >> 2;
    int sub = t & 3;
    if (e >= E) return;
    int e64 = flags[1];
    int wbf = flags[0];
    int r = ld_row(edge, e, e64);
    int c = ld_col(edge, e, e64);
    float p = 0.0f;
    if ((unsigned)r < (unsigned)GN && (unsigned)c < (unsigned)GN) {
        const uint4* pa = (const uint4*)(OUT + (size_t)r * GD + sub * 16);
        const uint4* pb = (const uint4*)(OUT + (size_t)c * GD + sub * 16);
        uint4 a0 = pa[0], a1 = pa[1];
        uint4 b0 = pb[0], b1 = pb[1];
        p = ((dot2_bf16(a0.x, b0.x) + dot2_bf16(a0.y, b0.y)) +
             (dot2_bf16(a0.z, b0.z) + dot2_bf16(a0.w, b0.w))) +
            ((dot2_bf16(a1.x, b1.x) + dot2_bf16(a1.y, b1.y)) +
             (dot2_bf16(a1.z, b1.z) + dot2_bf16(a1.w, b1.w)));
    }
    p += __shfl_down(p, 2, 4);
    p += __shfl_down(p, 1, 4);
    if (sub == 0) {
        if (wbf) ((__hip_bfloat16*)res)[e] = __float2bfloat16(p);
        else     ((float*)res)[e] = p;
    }
}

extern "C" void kernel_launch(void* const* d_in, const int* in_sizes, int n_in,
                              void* d_out, int out_size, void* d_ws, size_t ws_size,
                              hipStream_t stream) {
    const int E = GE, N = GN, ND = GN * GD;
    const int nblocks_scan = (N + SCAN_B - 1) / SCAN_B;  // 391

    const void* edge   = d_in[0];
    const void* weight = d_in[1];
    const void* alpha  = d_in[2];

    // Workspace layout (~45 MB total)
    char* ws = (char*)d_ws;
    int*   flags  = (int*)ws;   ws += 256;
    int*   degi   = (int*)ws;   ws += (((size_t)N * 4 + 255) / 256) * 256;
    float* dinv   = (float*)ws; ws += (((size_t)N * 4 + 255) / 256) * 256;
    int*   rowptr = (int*)ws;   ws += (((size_t)N * 4 + 255) / 256) * 256;
    int*   bsums  = (int*)ws;   ws += 2048;
    int*   csr    = (int*)ws;   ws += (size_t)E * 4;              // 4.8 MB
    __hip_bfloat16* X   = (__hip_bfloat16*)ws; ws += (size_t)ND * 2;  // 12.8 MB
    __hip_bfloat16* Y   = (__hip_bfloat16*)ws; ws += (size_t)ND * 2;  // 12.8 MB
    __hip_bfloat16* OUT = (__hip_bfloat16*)ws; ws += (size_t)ND * 2;  // 12.8 MB

    const int B = 256;

    detect_kernel<<<1, 256, 0, stream>>>(weight, edge, flags);

    // CSR build
    hipMemsetAsync(degi, 0, (size_t)N * 4, stream);
    hist_kernel<<<(E + B - 1) / B, B, 0, stream>>>((const int*)edge, flags, degi, E);
    scan1_kernel<<<nblocks_scan, SCAN_B, 0, stream>>>(degi, rowptr, bsums, dinv, N);
    scan2_kernel<<<1, 512, 0, stream>>>(bsums, nblocks_scan);
    scan3_kernel<<<nblocks_scan, SCAN_B, 0, stream>>>(rowptr, bsums, N);
    // XCD-affine fill: 8 col-range groups x 384 edge chunks
    {
        const int G = 384;
        const int chunkSize = (E + G - 1) / G;   // 3125
        fill_kernel<<<NXCD * G, B, 0, stream>>>((const int*)edge, flags, rowptr, csr,
                                                E, chunkSize);
    }

    // X = bf16(weight); OUT = bf16(a0*weight)
    init_kernel<<<(ND / 4 + B - 1) / B, B, 0, stream>>>(weight, alpha, flags, X, OUT, ND);

    // 3 propagation hops (gather + fused axpy; 2 edges/wave-step packed loads)
    const int ggrid = (int)(((size_t)N * 64 + B - 1) / B);
    gather_kernel<<<ggrid, B, 0, stream>>>(X, Y, OUT, rowptr, csr, dinv, alpha, flags, 1, 1, N);
    gather_kernel<<<ggrid, B, 0, stream>>>(Y, X, OUT, rowptr, csr, dinv, alpha, flags, 2, 1, N);
    gather_kernel<<<ggrid, B, 0, stream>>>(X, Y, OUT, rowptr, csr, dinv, alpha, flags, 3, 0, N);

    // per-edge link scores (4 threads/edge, 2x uint4 per row)
    dot_kernel<<<(int)(((size_t)E * 4 + B - 1) / B), B, 0, stream>>>(OUT, (const int*)edge, flags, d_out, E);
}

// Round 11
// 305.019 us; speedup vs baseline: 1.3184x; 1.2319x over previous
//
#include <hip/hip_runtime.h>
#include <hip/hip_bf16.h>

// Problem constants: N=100000 nodes, E=1200000 edges, D=64, K=3 hops.
#define GN 100000
#define GE 1200000
#define GD 64
#define NG 256                 // col groups
#define CPG 391                // cols per group (256*391 = 100096 >= GN)
#define CAP 6144               // bucket capacity per group (mean 4688, std 68)

// WS budget: round-4 showed ws_size < ~92 MB (overflow corrupted pristine
// inputs). This layout uses ~51 MB.
//
// CSR build history (rocprof):
//   r7 fill scatter 8B: WRITE 78 MB, 58 us   r8 4B: 83 MB, 96 us
//   r9 XCD-affine:      WRITE 50 MB, 57 us  (affinity can't fix evictions:
//   a csr line's ~16 partial writes are spread across the kernel; streaming
//   edge reads evict it between writes -> ~1 writeback per ENTRY.)
//   r11: two-phase radix partition -> all scatter runs against L2-hot windows
//   with LDS run-counters; hist/scan/fill kernels replaced by p1/gscan/p2
//   (p2's LDS histogram also yields dinv).

// ---------------------------------------------------------------------------
// Runtime dtype detection. flags[0]=1 if weight/alpha bf16 else fp32.
// flags[1]=1 if edge_index int64 else int32.
// ---------------------------------------------------------------------------
__global__ void detect_kernel(const void* __restrict__ w,
                              const void* __restrict__ edge,
                              int* __restrict__ flags) {
    __shared__ int s_badw, s_edgenz;
    if (threadIdx.x == 0) { s_badw = 0; s_edgenz = 0; }
    __syncthreads();
    const unsigned short* wh = (const unsigned short*)w;
    const unsigned int*   ei = (const unsigned int*)edge;
    int badw = 0, edgenz = 0;
    for (int i = threadIdx.x; i < 4096; i += 256) {
        unsigned int bits = ((unsigned int)wh[i]) << 16;
        float v = __uint_as_float(bits);
        if (!(fabsf(v) <= 100.0f)) badw = 1;         // NaN/Inf/huge -> fp32 backing
        if ((i & 1) == 1 && ei[i] != 0u) edgenz = 1; // odd word nonzero -> int32
    }
    if (badw)   atomicOr(&s_badw, 1);
    if (edgenz) atomicOr(&s_edgenz, 1);
    __syncthreads();
    if (threadIdx.x == 0) {
        flags[0] = s_badw ? 0 : 1;
        flags[1] = s_edgenz ? 0 : 1;
    }
}

__device__ __forceinline__ int ld_row(const int* __restrict__ edge, int e, int e64) {
    return e64 ? edge[2 * (size_t)e] : edge[e];
}
__device__ __forceinline__ int ld_col(const int* __restrict__ edge, int e, int e64) {
    return e64 ? edge[2 * ((size_t)GE + (size_t)e)] : edge[(size_t)GE + (size_t)e];
}
__device__ __forceinline__ float ld_f(const void* __restrict__ p, size_t i, int bf16f) {
    if (bf16f) return __bfloat162float(((const __hip_bfloat16*)p)[i]);
    return ((const float*)p)[i];
}

__device__ __forceinline__ float bf_lo(unsigned u) { return __uint_as_float(u << 16); }
__device__ __forceinline__ float bf_hi(unsigned u) { return __uint_as_float(u & 0xFFFF0000u); }
__device__ __forceinline__ unsigned bf16bits(float f) {
    __hip_bfloat16 h = __float2bfloat16(f);
    unsigned short s;
    __builtin_memcpy(&s, &h, 2);
    return (unsigned)s;
}

// ---- P1: partition edges into NG col-group buckets (packed (c_local<<17)|r) ----
__global__ void p1_kernel(const int* __restrict__ edge, const int* __restrict__ flags,
                          int* __restrict__ gcount, unsigned* __restrict__ bucket,
                          int E, int chunk) {
    __shared__ int cnt[NG];
    __shared__ int base[NG];
    int t = threadIdx.x;
    int e64 = flags[1];
    cnt[t] = 0;
    __syncthreads();
    int lo = blockIdx.x * chunk;
    int hiE = min(lo + chunk, E);
    // pass A: count valid edges per group
    for (int e = lo + t; e < hiE; e += 256) {
        int c = ld_col(edge, e, e64);
        int r = ld_row(edge, e, e64);
        if ((unsigned)c < (unsigned)GN && (unsigned)r < (unsigned)GN)
            atomicAdd(&cnt[c / CPG], 1);
    }
    __syncthreads();
    int cv = cnt[t];
    base[t] = (cv > 0) ? atomicAdd(&gcount[t], cv) : 0;
    __syncthreads();
    cnt[t] = 0;   // reuse as running offsets
    __syncthreads();
    // pass B: write entries
    for (int e = lo + t; e < hiE; e += 256) {
        int c = ld_col(edge, e, e64);
        int r = ld_row(edge, e, e64);
        if ((unsigned)c < (unsigned)GN && (unsigned)r < (unsigned)GN) {
            int g = c / CPG;
            int idx = base[g] + atomicAdd(&cnt[g], 1);
            if (idx < CAP)
                bucket[(size_t)g * CAP + idx] = ((unsigned)(c - g * CPG) << 17) | (unsigned)r;
        }
    }
}

// ---- exclusive scan of the NG group counts -> groupBase ----
__global__ void gscan_kernel(const int* __restrict__ gcount, int* __restrict__ groupBase) {
    __shared__ int s[NG];
    int t = threadIdx.x;
    int v = gcount[t]; if (v > CAP) v = CAP;
    s[t] = v;
    __syncthreads();
    for (int off = 1; off < NG; off <<= 1) {
        int u = (t >= off) ? s[t - off] : 0;
        __syncthreads();
        s[t] += u;
        __syncthreads();
    }
    groupBase[t] = s[t] - v;
}

// ---- P2: per group, LDS hist -> dinv + rowptr (coalesced) + csr fill (L2-hot) ----
__global__ void p2_kernel(const unsigned* __restrict__ bucket, const int* __restrict__ gcount,
                          const int* __restrict__ groupBase,
                          int* __restrict__ rowptr, float* __restrict__ dinv,
                          int* __restrict__ csr) {
    int g = blockIdx.x;
    int t = threadIdx.x;
    int m = gcount[g]; if (m > CAP) m = CAP;
    int gb = groupBase[g];
    __shared__ int hist[512];
    __shared__ int s[512];
    hist[t] = 0; hist[t + 256] = 0;
    __syncthreads();
    const unsigned* bk = bucket + (size_t)g * CAP;
    for (int idx = t; idx < m; idx += 256)
        atomicAdd(&hist[bk[idx] >> 17], 1);
    __syncthreads();
    int h0 = hist[t], h1 = hist[t + 256];
    s[t] = h0; s[t + 256] = h1;
    __syncthreads();
    for (int off = 1; off < 512; off <<= 1) {
        int v0 = (t >= off) ? s[t - off] : 0;
        int v1 = (t + 256 >= off) ? s[t + 256 - off] : 0;
        __syncthreads();
        s[t] += v0; s[t + 256] += v1;
        __syncthreads();
    }
    // s = inclusive scan; rowptr[col] = global END of segment (shift-trick order
    // preserved across groups since groups are ordered col ranges)
    int col0 = g * CPG + t;
    int col1 = col0 + 256;
    if (col0 < GN) {
        rowptr[col0] = gb + s[t];
        dinv[col0] = (h0 > 0) ? rsqrtf((float)h0) : 0.0f;
    }
    if (t + 256 < CPG && col1 < GN) {
        rowptr[col1] = gb + s[t + 256];
        dinv[col1] = (h1 > 0) ? rsqrtf((float)h1) : 0.0f;
    }
    __syncthreads();
    hist[t] = s[t] - h0;             // exclusive -> running counters
    hist[t + 256] = s[t + 256] - h1;
    __syncthreads();
    for (int idx = t; idx < m; idx += 256) {
        unsigned u = bk[idx];
        int cl = u >> 17;
        int r  = (int)(u & 0x1FFFFu);
        int pos = gb + atomicAdd(&hist[cl], 1);
        csr[pos] = r;
    }
}

// ---- X = bf16(weight); OUT = bf16(alpha[0] * weight) ----
__global__ void init_kernel(const void* __restrict__ w, const void* __restrict__ alpha,
                            const int* __restrict__ flags,
                            __hip_bfloat16* __restrict__ X, __hip_bfloat16* __restrict__ OUT,
                            int n) {
    int i = 4 * (blockIdx.x * blockDim.x + threadIdx.x);
    int wbf = flags[0];
    if (i < n) {
        float a0 = ld_f(alpha, 0, wbf);
        #pragma unroll
        for (int q = 0; q < 4; ++q) {
            float v = ld_f(w, i + q, wbf);
            X[i + q] = __float2bfloat16(v);        // hop-1 operand: exact bf16 input
            OUT[i + q] = __float2bfloat16(a0 * v);
        }
    }
}

// ---- one hop, gather form, fused axpy; 2 edges/wave-step, packed uint loads ----
__global__ void gather_kernel(const __hip_bfloat16* __restrict__ X,
                              __hip_bfloat16* __restrict__ Y,
                              __hip_bfloat16* __restrict__ OUT,
                              const int* __restrict__ rowptr, const int* __restrict__ csr,
                              const float* __restrict__ dinv,
                              const void* __restrict__ alpha, const int* __restrict__ flags,
                              int k, int store_y, int N) {
    int t = blockIdx.x * blockDim.x + threadIdx.x;
    int node = __builtin_amdgcn_readfirstlane(t >> 6);
    if (node >= N) return;
    int lane = t & 63;
    int h = lane >> 5;        // which edge of the pair
    int i = lane & 31;        // dim-pair index
    int beg = node ? rowptr[node - 1] : 0;   // rowptr[c] = segment end
    int end = rowptr[node];
    float dc = dinv[node];
    float ax0 = 0.0f, ay0 = 0.0f, ax1 = 0.0f, ay1 = 0.0f;
    float ax2 = 0.0f, ay2 = 0.0f, ax3 = 0.0f, ay3 = 0.0f;
    int j = beg;
    for (; j + 8 <= end; j += 8) {
        int r0 = csr[j + 0 + h];
        int r1 = csr[j + 2 + h];
        int r2 = csr[j + 4 + h];
        int r3 = csr[j + 6 + h];
        float w0 = dinv[r0]; float w1 = dinv[r1];
        float w2 = dinv[r2]; float w3 = dinv[r3];
        unsigned u0 = *(const unsigned*)(X + (size_t)r0 * GD + 2 * i);
        unsigned u1 = *(const unsigned*)(X + (size_t)r1 * GD + 2 * i);
        unsigned u2 = *(const unsigned*)(X + (size_t)r2 * GD + 2 * i);
        unsigned u3 = *(const unsigned*)(X + (size_t)r3 * GD + 2 * i);
        ax0 = fmaf(w0, bf_lo(u0), ax0); ay0 = fmaf(w0, bf_hi(u0), ay0);
        ax1 = fmaf(w1, bf_lo(u1), ax1); ay1 = fmaf(w1, bf_hi(u1), ay1);
        ax2 = fmaf(w2, bf_lo(u2), ax2); ay2 = fmaf(w2, bf_hi(u2), ay2);
        ax3 = fmaf(w3, bf_lo(u3), ax3); ay3 = fmaf(w3, bf_hi(u3), ay3);
    }
    for (; j + 2 <= end; j += 2) {
        int r = csr[j + h];
        float w = dinv[r];
        unsigned u = *(const unsigned*)(X + (size_t)r * GD + 2 * i);
        ax0 = fmaf(w, bf_lo(u), ax0); ay0 = fmaf(w, bf_hi(u), ay0);
    }
    if (j < end) {
        int r = csr[j];
        float w = (h == 0) ? dinv[r] : 0.0f;
        unsigned u = *(const unsigned*)(X + (size_t)r * GD + 2 * i);
        ax0 = fmaf(w, bf_lo(u), ax0); ay0 = fmaf(w, bf_hi(u), ay0);
    }
    float accx = (ax0 + ax1) + (ax2 + ax3);
    float accy = (ay0 + ay1) + (ay2 + ay3);
    accx += __shfl_xor(accx, 32, 64);
    accy += __shfl_xor(accy, 32, 64);
    accx *= dc; accy *= dc;
    float a = ld_f(alpha, k, flags[0]);
    if (h == 0) {
        __hip_bfloat16* yp = Y + (size_t)node * GD + 2 * i;
        __hip_bfloat16* op = OUT + (size_t)node * GD + 2 * i;
        if (store_y) {
            unsigned pack = (bf16bits(accy) << 16) | bf16bits(accx);
            *(unsigned*)yp = pack;
        }
        unsigned uo = *(const unsigned*)op;
        float ox = fmaf(a, accx, bf_lo(uo));
        float oy = fmaf(a, accy, bf_hi(uo));
        *(unsigned*)op = (bf16bits(oy) << 16) | bf16bits(ox);
    }
}

// ---- bf16-pair dot helper ----
__device__ __forceinline__ float dot2_bf16(unsigned ua, unsigned ub) {
    return fmaf(bf_lo(ua), bf_lo(ub), bf_hi(ua) * bf_hi(ub));
}

// ---- res[e] = dot(OUT[row[e]], OUT[col[e]]) — 4 threads/edge, 2x16B per row ----
__global__ void dot_kernel(const __hip_bfloat16* __restrict__ OUT,
                           const int* __restrict__ edge, const int* __restrict__ flags,
                           void* __restrict__ res, int E) {
    int t = blockIdx.x * blockDim.x + threadIdx.x;
    int e = t >> 2;
    int sub = t & 3;
    if (e >= E) return;
    int e64 = flags[1];
    int wbf = flags[0];
    int r = ld_row(edge, e, e64);
    int c = ld_col(edge, e, e64);
    float p = 0.0f;
    if ((unsigned)r < (unsigned)GN && (unsigned)c < (unsigned)GN) {
        const uint4* pa = (const uint4*)(OUT + (size_t)r * GD + sub * 16);
        const uint4* pb = (const uint4*)(OUT + (size_t)c * GD + sub * 16);
        uint4 a0 = pa[0], a1 = pa[1];
        uint4 b0 = pb[0], b1 = pb[1];
        p = ((dot2_bf16(a0.x, b0.x) + dot2_bf16(a0.y, b0.y)) +
             (dot2_bf16(a0.z, b0.z) + dot2_bf16(a0.w, b0.w))) +
            ((dot2_bf16(a1.x, b1.x) + dot2_bf16(a1.y, b1.y)) +
             (dot2_bf16(a1.z, b1.z) + dot2_bf16(a1.w, b1.w)));
    }
    p += __shfl_down(p, 2, 4);
    p += __shfl_down(p, 1, 4);
    if (sub == 0) {
        if (wbf) ((__hip_bfloat16*)res)[e] = __float2bfloat16(p);
        else     ((float*)res)[e] = p;
    }
}

extern "C" void kernel_launch(void* const* d_in, const int* in_sizes, int n_in,
                              void* d_out, int out_size, void* d_ws, size_t ws_size,
                              hipStream_t stream) {
    const int E = GE, N = GN, ND = GN * GD;

    const void* edge   = d_in[0];
    const void* weight = d_in[1];
    const void* alpha  = d_in[2];

    // Workspace layout (~51 MB total)
    char* ws = (char*)d_ws;
    int*      flags     = (int*)ws;      ws += 256;
    int*      gcount    = (int*)ws;      ws += 1024;
    int*      groupBase = (int*)ws;      ws += 1024;
    float*    dinv      = (float*)ws;    ws += (((size_t)N * 4 + 255) / 256) * 256;
    int*      rowptr    = (int*)ws;      ws += (((size_t)N * 4 + 255) / 256) * 256;
    unsigned* bucket    = (unsigned*)ws; ws += (size_t)NG * CAP * 4;   // 6.3 MB
    int*      csr       = (int*)ws;      ws += (size_t)E * 4;          // 4.8 MB
    __hip_bfloat16* X   = (__hip_bfloat16*)ws; ws += (size_t)ND * 2;   // 12.8 MB
    __hip_bfloat16* Y   = (__hip_bfloat16*)ws; ws += (size_t)ND * 2;   // 12.8 MB
    __hip_bfloat16* OUT = (__hip_bfloat16*)ws; ws += (size_t)ND * 2;   // 12.8 MB

    const int B = 256;

    detect_kernel<<<1, 256, 0, stream>>>(weight, edge, flags);

    // CSR build: radix partition (p1) -> group scan -> per-group build (p2)
    hipMemsetAsync(gcount, 0, NG * 4, stream);
    {
        const int P1B = 256;
        const int chunk = (E + P1B - 1) / P1B;   // 4688
        p1_kernel<<<P1B, 256, 0, stream>>>((const int*)edge, flags, gcount, bucket, E, chunk);
    }
    gscan_kernel<<<1, NG, 0, stream>>>(gcount, groupBase);
    p2_kernel<<<NG, 256, 0, stream>>>(bucket, gcount, groupBase, rowptr, dinv, csr);

    // X = bf16(weight); OUT = bf16(a0*weight)
    init_kernel<<<(ND / 4 + B - 1) / B, B, 0, stream>>>(weight, alpha, flags, X, OUT, ND);

    // 3 propagation hops (gather + fused axpy; 2 edges/wave-step packed loads)
    const int ggrid = (int)(((size_t)N * 64 + B - 1) / B);
    gather_kernel<<<ggrid, B, 0, stream>>>(X, Y, OUT, rowptr, csr, dinv, alpha, flags, 1, 1, N);
    gather_kernel<<<ggrid, B, 0, stream>>>(Y, X, OUT, rowptr, csr, dinv, alpha, flags, 2, 1, N);
    gather_kernel<<<ggrid, B, 0, stream>>>(X, Y, OUT, rowptr, csr, dinv, alpha, flags, 3, 0, N);

    // per-edge link scores (4 threads/edge, 2x uint4 per row)
    dot_kernel<<<(int)(((size_t)E * 4 + B - 1) / B), B, 0, stream>>>(OUT, (const int*)edge, flags, d_out, E);
}

// Round 12
// 286.894 us; speedup vs baseline: 1.4017x; 1.0632x over previous
//
#include <hip/hip_runtime.h>
#include <hip/hip_bf16.h>

// Problem constants: N=100000 nodes, E=1200000 edges, D=64, K=3 hops.
#define GN 100000
#define GE 1200000
#define GD 64
#define NG 256                 // col groups
#define CPG 391                // cols per group (256*391 = 100096 >= GN)
#define CAP 6144               // bucket capacity per group (mean 4688, std 68)

// WS budget: round-4 showed ws_size < ~92 MB (overflow corrupted pristine
// inputs). This layout uses ~51 MB.
//
// CSR build: two-phase radix partition (r11) replaced the scatter fill whose
// cross-XCD 64B-line writebacks cost ~1 per ENTRY (r7-r9 history in git log).
// r12: gather restructured for latency (4 edges/step, predicated 16-edge
// block -> dependent rounds 6->3); memset+gscan dispatches folded away.

// ---------------------------------------------------------------------------
// Runtime dtype detection. flags[0]=1 if weight/alpha bf16 else fp32.
// flags[1]=1 if edge_index int64 else int32.  Also zeroes gcount (saves a
// memset dispatch; stream order guarantees completion before p1).
// ---------------------------------------------------------------------------
__global__ void detect_kernel(const void* __restrict__ w,
                              const void* __restrict__ edge,
                              int* __restrict__ flags, int* __restrict__ gcount) {
    __shared__ int s_badw, s_edgenz;
    if (threadIdx.x == 0) { s_badw = 0; s_edgenz = 0; }
    gcount[threadIdx.x] = 0;
    __syncthreads();
    const unsigned short* wh = (const unsigned short*)w;
    const unsigned int*   ei = (const unsigned int*)edge;
    int badw = 0, edgenz = 0;
    for (int i = threadIdx.x; i < 4096; i += 256) {
        unsigned int bits = ((unsigned int)wh[i]) << 16;
        float v = __uint_as_float(bits);
        if (!(fabsf(v) <= 100.0f)) badw = 1;         // NaN/Inf/huge -> fp32 backing
        if ((i & 1) == 1 && ei[i] != 0u) edgenz = 1; // odd word nonzero -> int32
    }
    if (badw)   atomicOr(&s_badw, 1);
    if (edgenz) atomicOr(&s_edgenz, 1);
    __syncthreads();
    if (threadIdx.x == 0) {
        flags[0] = s_badw ? 0 : 1;
        flags[1] = s_edgenz ? 0 : 1;
    }
}

__device__ __forceinline__ int ld_row(const int* __restrict__ edge, int e, int e64) {
    return e64 ? edge[2 * (size_t)e] : edge[e];
}
__device__ __forceinline__ int ld_col(const int* __restrict__ edge, int e, int e64) {
    return e64 ? edge[2 * ((size_t)GE + (size_t)e)] : edge[(size_t)GE + (size_t)e];
}
__device__ __forceinline__ float ld_f(const void* __restrict__ p, size_t i, int bf16f) {
    if (bf16f) return __bfloat162float(((const __hip_bfloat16*)p)[i]);
    return ((const float*)p)[i];
}

__device__ __forceinline__ float bf_lo(unsigned u) { return __uint_as_float(u << 16); }
__device__ __forceinline__ float bf_hi(unsigned u) { return __uint_as_float(u & 0xFFFF0000u); }
__device__ __forceinline__ unsigned bf16bits(float f) {
    __hip_bfloat16 h = __float2bfloat16(f);
    unsigned short s;
    __builtin_memcpy(&s, &h, 2);
    return (unsigned)s;
}

// ---- P1: partition edges into NG col-group buckets (packed (c_local<<17)|r) ----
__global__ void p1_kernel(const int* __restrict__ edge, const int* __restrict__ flags,
                          int* __restrict__ gcount, unsigned* __restrict__ bucket,
                          int E, int chunk) {
    __shared__ int cnt[NG];
    __shared__ int base[NG];
    int t = threadIdx.x;
    int e64 = flags[1];
    cnt[t] = 0;
    __syncthreads();
    int lo = blockIdx.x * chunk;
    int hiE = min(lo + chunk, E);
    // pass A: count valid edges per group
    for (int e = lo + t; e < hiE; e += 256) {
        int c = ld_col(edge, e, e64);
        int r = ld_row(edge, e, e64);
        if ((unsigned)c < (unsigned)GN && (unsigned)r < (unsigned)GN)
            atomicAdd(&cnt[c / CPG], 1);
    }
    __syncthreads();
    int cv = cnt[t];
    base[t] = (cv > 0) ? atomicAdd(&gcount[t], cv) : 0;
    __syncthreads();
    cnt[t] = 0;   // reuse as running offsets
    __syncthreads();
    // pass B: write entries
    for (int e = lo + t; e < hiE; e += 256) {
        int c = ld_col(edge, e, e64);
        int r = ld_row(edge, e, e64);
        if ((unsigned)c < (unsigned)GN && (unsigned)r < (unsigned)GN) {
            int g = c / CPG;
            int idx = base[g] + atomicAdd(&cnt[g], 1);
            if (idx < CAP)
                bucket[(size_t)g * CAP + idx] = ((unsigned)(c - g * CPG) << 17) | (unsigned)r;
        }
    }
}

// ---- P2: per group, self-scan gcount -> base; LDS hist -> dinv + rowptr + csr ----
__global__ void p2_kernel(const unsigned* __restrict__ bucket, const int* __restrict__ gcount,
                          int* __restrict__ rowptr, float* __restrict__ dinv,
                          int* __restrict__ csr) {
    int g = blockIdx.x;
    int t = threadIdx.x;
    __shared__ int gs[NG];
    __shared__ int hist[512];
    __shared__ int s[512];
    int gv = gcount[t]; if (gv > CAP) gv = CAP;
    gs[t] = gv;
    hist[t] = 0; hist[t + 256] = 0;
    __syncthreads();
    for (int off = 1; off < NG; off <<= 1) {
        int u = (t >= off) ? gs[t - off] : 0;
        __syncthreads();
        gs[t] += u;
        __syncthreads();
    }
    int mg = gcount[g]; if (mg > CAP) mg = CAP;
    int gb = gs[g] - mg;          // exclusive group base
    int m = mg;
    const unsigned* bk = bucket + (size_t)g * CAP;
    for (int idx = t; idx < m; idx += 256)
        atomicAdd(&hist[bk[idx] >> 17], 1);
    __syncthreads();
    int h0 = hist[t], h1 = hist[t + 256];
    s[t] = h0; s[t + 256] = h1;
    __syncthreads();
    for (int off = 1; off < 512; off <<= 1) {
        int v0 = (t >= off) ? s[t - off] : 0;
        int v1 = (t + 256 >= off) ? s[t + 256 - off] : 0;
        __syncthreads();
        s[t] += v0; s[t + 256] += v1;
        __syncthreads();
    }
    // s = inclusive scan; rowptr[col] = global END of segment
    int col0 = g * CPG + t;
    int col1 = col0 + 256;
    if (col0 < GN) {
        rowptr[col0] = gb + s[t];
        dinv[col0] = (h0 > 0) ? rsqrtf((float)h0) : 0.0f;
    }
    if (t + 256 < CPG && col1 < GN) {
        rowptr[col1] = gb + s[t + 256];
        dinv[col1] = (h1 > 0) ? rsqrtf((float)h1) : 0.0f;
    }
    __syncthreads();
    hist[t] = s[t] - h0;             // exclusive -> running counters
    hist[t + 256] = s[t + 256] - h1;
    __syncthreads();
    for (int idx = t; idx < m; idx += 256) {
        unsigned u = bk[idx];
        int cl = u >> 17;
        int r  = (int)(u & 0x1FFFFu);
        int pos = gb + atomicAdd(&hist[cl], 1);
        csr[pos] = r;
    }
}

// ---- X = bf16(weight); OUT = bf16(alpha[0] * weight) ----
__global__ void init_kernel(const void* __restrict__ w, const void* __restrict__ alpha,
                            const int* __restrict__ flags,
                            __hip_bfloat16* __restrict__ X, __hip_bfloat16* __restrict__ OUT,
                            int n) {
    int i = 4 * (blockIdx.x * blockDim.x + threadIdx.x);
    int wbf = flags[0];
    if (i < n) {
        float a0 = ld_f(alpha, 0, wbf);
        #pragma unroll
        for (int q = 0; q < 4; ++q) {
            float v = ld_f(w, i + q, wbf);
            X[i + q] = __float2bfloat16(v);        // hop-1 operand: exact bf16 input
            OUT[i + q] = __float2bfloat16(a0 * v);
        }
    }
}

// ---- one hop, gather form, fused axpy; 4 edges/step (16 lanes x uint2),
// fully-predicated 16-edge block: one csr round + one dinv/X round covers
// deg<=16 (~90% of nodes). OUT row + alpha prefetched before the loop. ----
__global__ void gather_kernel(const __hip_bfloat16* __restrict__ X,
                              __hip_bfloat16* __restrict__ Y,
                              __hip_bfloat16* __restrict__ OUT,
                              const int* __restrict__ rowptr, const int* __restrict__ csr,
                              const float* __restrict__ dinv,
                              const void* __restrict__ alpha, const int* __restrict__ flags,
                              int k, int store_y, int N) {
    int t = blockIdx.x * blockDim.x + threadIdx.x;
    int node = __builtin_amdgcn_readfirstlane(t >> 6);
    if (node >= N) return;
    int lane = t & 63;
    int h = lane >> 4;        // edge slot within a 4-edge step
    int i = lane & 15;        // dim-quad index (dims 4i..4i+3)
    // independent early loads (all hidden under the edge loop)
    int beg = node ? rowptr[node - 1] : 0;   // rowptr[c] = segment end
    int end = rowptr[node];
    float dc = dinv[node];
    float a = ld_f(alpha, k, flags[0]);
    size_t obase = (size_t)node * GD + 4 * i;
    uint2 uo = *(const uint2*)(OUT + obase);  // OUT row prefetch
    float f0 = 0.0f, f1 = 0.0f, f2 = 0.0f, f3 = 0.0f;
    for (int j = beg; j < end; j += 16) {
        int i0 = j + 0 + h;  int i1 = j + 4 + h;
        int i2 = j + 8 + h;  int i3 = j + 12 + h;
        int last = end - 1;
        int r0 = csr[min(i0, last)];
        int r1 = csr[min(i1, last)];
        int r2 = csr[min(i2, last)];
        int r3 = csr[min(i3, last)];
        float w0 = (i0 < end) ? dinv[r0] : 0.0f;
        float w1 = (i1 < end) ? dinv[r1] : 0.0f;
        float w2 = (i2 < end) ? dinv[r2] : 0.0f;
        float w3 = (i3 < end) ? dinv[r3] : 0.0f;
        uint2 u0 = *(const uint2*)(X + (size_t)r0 * GD + 4 * i);
        uint2 u1 = *(const uint2*)(X + (size_t)r1 * GD + 4 * i);
        uint2 u2 = *(const uint2*)(X + (size_t)r2 * GD + 4 * i);
        uint2 u3 = *(const uint2*)(X + (size_t)r3 * GD + 4 * i);
        f0 = fmaf(w0, bf_lo(u0.x), f0); f1 = fmaf(w0, bf_hi(u0.x), f1);
        f2 = fmaf(w0, bf_lo(u0.y), f2); f3 = fmaf(w0, bf_hi(u0.y), f3);
        f0 = fmaf(w1, bf_lo(u1.x), f0); f1 = fmaf(w1, bf_hi(u1.x), f1);
        f2 = fmaf(w1, bf_lo(u1.y), f2); f3 = fmaf(w1, bf_hi(u1.y), f3);
        f0 = fmaf(w2, bf_lo(u2.x), f0); f1 = fmaf(w2, bf_hi(u2.x), f1);
        f2 = fmaf(w2, bf_lo(u2.y), f2); f3 = fmaf(w2, bf_hi(u2.y), f3);
        f0 = fmaf(w3, bf_lo(u3.x), f0); f1 = fmaf(w3, bf_hi(u3.x), f1);
        f2 = fmaf(w3, bf_lo(u3.y), f2); f3 = fmaf(w3, bf_hi(u3.y), f3);
    }
    // combine the 4 edge slots (disjoint edge subsets)
    f0 += __shfl_xor(f0, 16, 64); f0 += __shfl_xor(f0, 32, 64);
    f1 += __shfl_xor(f1, 16, 64); f1 += __shfl_xor(f1, 32, 64);
    f2 += __shfl_xor(f2, 16, 64); f2 += __shfl_xor(f2, 32, 64);
    f3 += __shfl_xor(f3, 16, 64); f3 += __shfl_xor(f3, 32, 64);
    f0 *= dc; f1 *= dc; f2 *= dc; f3 *= dc;
    if (h == 0) {
        if (store_y) {
            uint2 p;
            p.x = (bf16bits(f1) << 16) | bf16bits(f0);
            p.y = (bf16bits(f3) << 16) | bf16bits(f2);
            *(uint2*)(Y + obase) = p;
        }
        float o0 = fmaf(a, f0, bf_lo(uo.x));
        float o1 = fmaf(a, f1, bf_hi(uo.x));
        float o2 = fmaf(a, f2, bf_lo(uo.y));
        float o3 = fmaf(a, f3, bf_hi(uo.y));
        uint2 q;
        q.x = (bf16bits(o1) << 16) | bf16bits(o0);
        q.y = (bf16bits(o3) << 16) | bf16bits(o2);
        *(uint2*)(OUT + obase) = q;
    }
}

// ---- bf16-pair dot helper ----
__device__ __forceinline__ float dot2_bf16(unsigned ua, unsigned ub) {
    return fmaf(bf_lo(ua), bf_lo(ub), bf_hi(ua) * bf_hi(ub));
}

// ---- res[e] = dot(OUT[row[e]], OUT[col[e]]) — 4 threads/edge, 2x16B per row ----
__global__ void dot_kernel(const __hip_bfloat16* __restrict__ OUT,
                           const int* __restrict__ edge, const int* __restrict__ flags,
                           void* __restrict__ res, int E) {
    int t = blockIdx.x * blockDim.x + threadIdx.x;
    int e = t >> 2;
    int sub = t & 3;
    if (e >= E) return;
    int e64 = flags[1];
    int wbf = flags[0];
    int r = ld_row(edge, e, e64);
    int c = ld_col(edge, e, e64);
    float p = 0.0f;
    if ((unsigned)r < (unsigned)GN && (unsigned)c < (unsigned)GN) {
        const uint4* pa = (const uint4*)(OUT + (size_t)r * GD + sub * 16);
        const uint4* pb = (const uint4*)(OUT + (size_t)c * GD + sub * 16);
        uint4 a0 = pa[0], a1 = pa[1];
        uint4 b0 = pb[0], b1 = pb[1];
        p = ((dot2_bf16(a0.x, b0.x) + dot2_bf16(a0.y, b0.y)) +
             (dot2_bf16(a0.z, b0.z) + dot2_bf16(a0.w, b0.w))) +
            ((dot2_bf16(a1.x, b1.x) + dot2_bf16(a1.y, b1.y)) +
             (dot2_bf16(a1.z, b1.z) + dot2_bf16(a1.w, b1.w)));
    }
    p += __shfl_down(p, 2, 4);
    p += __shfl_down(p, 1, 4);
    if (sub == 0) {
        if (wbf) ((__hip_bfloat16*)res)[e] = __float2bfloat16(p);
        else     ((float*)res)[e] = p;
    }
}

extern "C" void kernel_launch(void* const* d_in, const int* in_sizes, int n_in,
                              void* d_out, int out_size, void* d_ws, size_t ws_size,
                              hipStream_t stream) {
    const int E = GE, N = GN, ND = GN * GD;

    const void* edge   = d_in[0];
    const void* weight = d_in[1];
    const void* alpha  = d_in[2];

    // Workspace layout (~51 MB total)
    char* ws = (char*)d_ws;
    int*      flags     = (int*)ws;      ws += 256;
    int*      gcount    = (int*)ws;      ws += 1024;
    float*    dinv      = (float*)ws;    ws += (((size_t)N * 4 + 255) / 256) * 256;
    int*      rowptr    = (int*)ws;      ws += (((size_t)N * 4 + 255) / 256) * 256;
    unsigned* bucket    = (unsigned*)ws; ws += (size_t)NG * CAP * 4;   // 6.3 MB
    int*      csr       = (int*)ws;      ws += (size_t)E * 4;          // 4.8 MB
    __hip_bfloat16* X   = (__hip_bfloat16*)ws; ws += (size_t)ND * 2;   // 12.8 MB
    __hip_bfloat16* Y   = (__hip_bfloat16*)ws; ws += (size_t)ND * 2;   // 12.8 MB
    __hip_bfloat16* OUT = (__hip_bfloat16*)ws; ws += (size_t)ND * 2;   // 12.8 MB

    const int B = 256;

    detect_kernel<<<1, 256, 0, stream>>>(weight, edge, flags, gcount);

    // CSR build: radix partition (p1) -> per-group build w/ self-scan (p2)
    {
        const int P1B = 256;
        const int chunk = (E + P1B - 1) / P1B;   // 4688
        p1_kernel<<<P1B, 256, 0, stream>>>((const int*)edge, flags, gcount, bucket, E, chunk);
    }
    p2_kernel<<<NG, 256, 0, stream>>>(bucket, gcount, rowptr, dinv, csr);

    // X = bf16(weight); OUT = bf16(a0*weight)
    init_kernel<<<(ND / 4 + B - 1) / B, B, 0, stream>>>(weight, alpha, flags, X, OUT, ND);

    // 3 propagation hops (gather + fused axpy; 4 edges/step predicated blocks)
    const int ggrid = (int)(((size_t)N * 64 + B - 1) / B);
    gather_kernel<<<ggrid, B, 0, stream>>>(X, Y, OUT, rowptr, csr, dinv, alpha, flags, 1, 1, N);
    gather_kernel<<<ggrid, B, 0, stream>>>(Y, X, OUT, rowptr, csr, dinv, alpha, flags, 2, 1, N);
    gather_kernel<<<ggrid, B, 0, stream>>>(X, Y, OUT, rowptr, csr, dinv, alpha, flags, 3, 0, N);

    // per-edge link scores (4 threads/edge, 2x uint4 per row)
    dot_kernel<<<(int)(((size_t)E * 4 + B - 1) / B), B, 0, stream>>>(OUT, (const int*)edge, flags, d_out, E);
}